// Round 8
// baseline (582.147 us; speedup 1.0000x reference)
//
#include <hip/hip_runtime.h>

#define HW 4096
#define CC 256
#define KK 2048
#define BB 16
#define NN (BB*HW)          // 65536

// d_out layout (floats): [z_q 16777216][idx 65536][loss 1][probs 134217728]
#define ZQ_SZ   (BB*CC*HW)
#define IDX_OFF ZQ_SZ
#define LOSS_OFF (IDX_OFF + NN)
#define PROBS_OFF (LOSS_OFF + 1)

// scratch parked in z_q region (float offsets), overwritten by k_zq at the end
#define EH_OFF 0          // eh[K][C] bf16 (rn) = 262144 floats
#define EE_OFF 262144     // ee_np[K] f32

#define TAU 0.01f
#define CAND_CAP 2048
#define KTC 64            // codes per k-tile
#define KT_N 32           // tiles per pass

typedef short bf16x8 __attribute__((ext_vector_type(8)));
typedef float f32x16 __attribute__((ext_vector_type(16)));

__device__ __forceinline__ unsigned short bf16rn(float x){
  unsigned u = __float_as_uint(x);
  return (unsigned short)((u + 0x7fffu + ((u >> 16) & 1u)) >> 16);
}

// ---- numpy pairwise sum-of-squares over 256 elems (PW_BLOCKSIZE=128) ----
template<int STRIDE>
__device__ __forceinline__ float np_sumsq256(const float* __restrict__ a){
  float res0 = 0.f, res1 = 0.f;
  #pragma unroll
  for (int h = 0; h < 2; h++){
    const float* p = a + (size_t)h * 128 * STRIDE;
    float r[8];
    #pragma unroll
    for (int j = 0; j < 8; j++){ float x = p[(size_t)j * STRIDE]; r[j] = __fmul_rn(x, x); }
    for (int i = 8; i < 128; i += 8){
      #pragma unroll
      for (int j = 0; j < 8; j++){
        float x = p[(size_t)(i + j) * STRIDE];
        r[j] = __fadd_rn(r[j], __fmul_rn(x, x));
      }
    }
    float s = __fadd_rn(__fadd_rn(__fadd_rn(r[0], r[1]), __fadd_rn(r[2], r[3])),
                        __fadd_rn(__fadd_rn(r[4], r[5]), __fadd_rn(r[6], r[7])));
    if (h == 0) res0 = s; else res1 = s;
  }
  return __fadd_rn(res0, res1);
}

// ---------------- prep: bf16(rn) codebook + np-exact ee ----------------
__global__ void k_prep2(const float* __restrict__ cb, float* __restrict__ out){
  const int k = blockIdx.x * 256 + threadIdx.x;   // 8 blocks
  unsigned short* eh = (unsigned short*)(out + EH_OFF);
  const float* row = cb + (size_t)k * CC;
  for (int c = 0; c < CC; c++) eh[k * CC + c] = bf16rn(row[c]);
  out[EE_OFF + k] = np_sumsq256<1>(row);
}

// ---------------- main MFMA kernel: 256 rows x 2048 codes per block ----------------
// lds_e[buf][cs 16][sub 2][code 64][16B]; mfma(e, z) -> D[code][zrow]
__global__ __launch_bounds__(512, 2)
void k_mfma(const float* __restrict__ feats, const float* __restrict__ cb,
            float* __restrict__ out){
  __shared__ __align__(16) unsigned char lds_e[2][32768];
  __shared__ float ee_lds[KK];
  __shared__ unsigned long long rowkey[256];
  __shared__ int cand[CAND_CAP];
  __shared__ int cand_n;
  __shared__ float lsum;

  const int t = threadIdx.x;
  const int w = t >> 6, l = t & 63;
  const int n0 = blockIdx.x * 256;       // 256 blocks
  const int bi = n0 >> 12;
  const int hw0 = n0 & 4095;
  const int grp = l >> 5;
  const int code_l = l & 31;
  const int zrow = l & 31;
  const int myhw = hw0 + w * 32 + zrow;

  for (int i = t; i < KK; i += 512) ee_lds[i] = out[EE_OFF + i];
  if (t < 256) rowkey[t] = ~0ull;
  if (t == 0){ cand_n = 0; lsum = 0.f; }

  // ---- z fragments (B operand): z[c][zrow], resident in VGPRs
  bf16x8 ah[16];
  {
    const float* zb = feats + (size_t)bi * CC * HW + myhw;
    #pragma unroll
    for (int cs = 0; cs < 16; ++cs){
      #pragma unroll
      for (int j = 0; j < 8; ++j)
        ah[cs][j] = (short)bf16rn(zb[(size_t)(cs * 16 + grp * 8 + j) * HW]);
    }
  }

  const unsigned short* ehg = (const unsigned short*)(out + EH_OFF);
  float4 stg[4];

#define VLOAD(KT) { \
    _Pragma("unroll") \
    for (int i_ = 0; i_ < 4; ++i_){ \
      int ix_ = i_ * 512 + t; \
      int cd_ = ix_ & 63; \
      int g_  = (ix_ >> 6) & 1; \
      int cs_ = ix_ >> 7; \
      stg[i_] = *(const float4*)(ehg + (size_t)((KT) * KTC + cd_) * CC + cs_ * 16 + g_ * 8); \
    } }

#define DSWRITE(B) { \
    _Pragma("unroll") \
    for (int i_ = 0; i_ < 4; ++i_) *(float4*)(&lds_e[B][(i_ * 512 + t) * 16]) = stg[i_]; }

  // e as A-operand, z as B-operand: D[code][zrow]; 2 chains (code halves)
#define COMPUTE(B) { \
    _Pragma("unroll") \
    for (int ii = 0; ii < 16; ++ii){ accA[ii] = 0.f; accB[ii] = 0.f; } \
    _Pragma("unroll") \
    for (int cs = 0; cs < 16; ++cs){ \
      const unsigned char* bp_ = &lds_e[B][(size_t)(cs * 2 + grp) * 1024 + code_l * 16]; \
      bf16x8 e0_ = *(const bf16x8*)(bp_); \
      bf16x8 e1_ = *(const bf16x8*)(bp_ + 512); \
      accA = __builtin_amdgcn_mfma_f32_32x32x16_bf16(e0_, ah[cs], accA, 0, 0, 0); \
      accB = __builtin_amdgcn_mfma_f32_32x32x16_bf16(e1_, ah[cs], accB, 0, 0, 0); \
    } }

  f32x16 accA, accB;
  float m_ = 3e38f, ss_ = 0.f, inv_ = 0.f;

  // prologue: stage tile 0 into buf 0
  VLOAD(0); DSWRITE(0);
  __syncthreads();

  // fused loop: kt<32 = pass 1 (stats), kt>=32 = pass 2 (probs+cands)
  for (int kt = 0; kt < 2 * KT_N; ++kt){
    const int tt = kt & 31;
    const int nb = kt & 1;
    if (kt < 2 * KT_N - 1) VLOAD((kt + 1) & 31);   // issue next-tile loads early
    COMPUTE(nb);
    const int eebase = tt * 64 + 4 * grp;
    if (kt < KT_N){
      #pragma unroll
      for (int r = 0; r < 16; ++r){
        int off = (r & 3) + 8 * (r >> 2);
        float s0 = ee_lds[eebase + off]      - 2.f * accA[r];
        float s1 = ee_lds[eebase + off + 32] - 2.f * accB[r];
        m_ = fminf(m_, fminf(s0, s1));
        ss_ += __expf(-s0) + __expf(-s1);     // s in [-1,1]: shift-free
      }
      if (kt == KT_N - 1){                    // merge grp halves, finalize
        m_ = fminf(m_, __shfl_xor(m_, 32));
        ss_ += __shfl_xor(ss_, 32);
        inv_ = 1.f / ss_;
      }
    } else {
      #pragma unroll
      for (int r = 0; r < 16; ++r){
        int off = (r & 3) + 8 * (r >> 2);
        int cg = tt * 64 + 4 * grp + off;     // global code for accA[r]
        float s0 = ee_lds[eebase + off]      - 2.f * accA[r];
        float s1 = ee_lds[eebase + off + 32] - 2.f * accB[r];
        float* p0 = out + (size_t)PROBS_OFF + (size_t)(bi * KK + cg) * HW + myhw;
        __builtin_nontemporal_store(__expf(-s0) * inv_, p0);
        __builtin_nontemporal_store(__expf(-s1) * inv_, p0 + (size_t)32 * HW);
        if (s0 <= m_ + TAU){
          int sl = atomicAdd(&cand_n, 1);
          if (sl < CAND_CAP) cand[sl] = ((w * 32 + zrow) << 16) | cg;
        }
        if (s1 <= m_ + TAU){
          int sl = atomicAdd(&cand_n, 1);
          if (sl < CAND_CAP) cand[sl] = ((w * 32 + zrow) << 16) | (cg + 32);
        }
      }
    }
    if (kt < 2 * KT_N - 1) DSWRITE(nb ^ 1);   // other buffer: no hazard w/ readers
    __syncthreads();                          // one barrier per tile
  }

  // ---- bit-exact rescore of candidates (numpy fp32 chain), first-min wins
  int nc = cand_n; if (nc > CAND_CAP) nc = CAND_CAP;
  for (int i = t; i < nc; i += 512){
    int rc = cand[i];
    int rl = rc >> 16, code = rc & 0xffff;
    int n = n0 + rl;
    const float* zp = feats + (size_t)(n >> 12) * CC * HW + (n & 4095);
    const float* ep = cb + (size_t)code * CC;
    float a = 0.f;
    #pragma unroll 8
    for (int c = 0; c < CC; ++c) a = __builtin_fmaf(zp[(size_t)c * HW], ep[c], a);
    float zzv = np_sumsq256<HW>(zp);          // np-exact ||z||^2 on demand
    float t1 = __fadd_rn(zzv, ee_lds[code]);
    float d = __fadd_rn(t1, -2.f * a);
    unsigned long long key = ((unsigned long long)__float_as_uint(d) << 32) | (unsigned)code;
    atomicMin(&rowkey[rl], key);
  }
  __syncthreads();

  if (t < 256) out[IDX_OFF + n0 + t] = (float)(int)(rowkey[t] & 0xffffffffu);

  // ---- loss: sum (cb[idx]-z)^2 over block rows
  {
    int rl = w * 32 + (l & 31);
    int code = (int)(rowkey[rl] & 0xffffffffu);
    const float* ep = cb + (size_t)code * CC;
    int n = n0 + rl;
    const float* zp = feats + (size_t)(n >> 12) * CC * HW + (n & 4095);
    float s = 0.f;
    int c0 = grp * 128;
    for (int c = c0; c < c0 + 128; ++c){
      float dz = ep[c] - zp[(size_t)c * HW];
      s = __builtin_fmaf(dz, dz, s);
    }
    s += __shfl_xor(s, 32);
    if (grp == 0) atomicAdd(&lsum, s);
  }
  __syncthreads();
  if (t == 0) atomicAdd(out + LOSS_OFF, lsum * (1.25f / 16777216.f));
}

// ---------------- z_q gather (bit-exact copy; overwrites scratch) ----------------
__global__ void k_zq(const float* __restrict__ cb, float* __restrict__ out){
  const int f4 = blockIdx.x * 256 + threadIdx.x;  // 16384 blocks
  const int f = f4 * 4;
  const int b = f >> 20;
  const int rem = f & 1048575;
  const int c = rem >> 12;
  const int hw = rem & 4095;
  const int n = b * HW + hw;
  const float* idxf = out + IDX_OFF;
  float4 iv = *(const float4*)(idxf + n);
  float4 o;
  o.x = cb[(size_t)((int)iv.x) * CC + c];
  o.y = cb[(size_t)((int)iv.y) * CC + c];
  o.z = cb[(size_t)((int)iv.z) * CC + c];
  o.w = cb[(size_t)((int)iv.w) * CC + c];
  *(float4*)(out + f) = o;
}

extern "C" void kernel_launch(void* const* d_in, const int* in_sizes, int n_in,
                              void* d_out, int out_size, void* d_ws, size_t ws_size,
                              hipStream_t stream){
  const float* feats = (const float*)d_in[0];
  const float* cb    = (const float*)d_in[1];
  float* out = (float*)d_out;

  (void)hipMemsetAsync(out + LOSS_OFF, 0, sizeof(float), stream);
  hipLaunchKernelGGL(k_prep2, dim3(8),     dim3(256), 0, stream, cb, out);
  hipLaunchKernelGGL(k_mfma,  dim3(256),   dim3(512), 0, stream, feats, cb, out);
  hipLaunchKernelGGL(k_zq,    dim3(16384), dim3(256), 0, stream, cb, out);
}

// Round 9
// 531.852 us; speedup vs baseline: 1.0946x; 1.0946x over previous
//
#include <hip/hip_runtime.h>

#define HW 4096
#define CC 256
#define KK 2048
#define BB 16
#define NN (BB*HW)          // 65536

// d_out layout (floats): [z_q 16777216][idx 65536][loss 1][probs 134217728]
#define ZQ_SZ   (BB*CC*HW)
#define IDX_OFF ZQ_SZ
#define LOSS_OFF (IDX_OFF + NN)
#define PROBS_OFF (LOSS_OFF + 1)

// scratch parked in z_q region (float offsets), overwritten by k_zq at the end
#define EH_OFF 0          // eh[K][C] bf16 (rn) = 262144 floats
#define EE_OFF 262144     // ee_np[K] f32
#define ZZ_OFF 264192     // zz_np[N] f32

#define TAU 0.01f
#define CAND_CAP 768
#define KTC 64            // codes per k-tile
#define KT_N 32           // tiles per pass

typedef short bf16x8 __attribute__((ext_vector_type(8)));
typedef float f32x16 __attribute__((ext_vector_type(16)));
typedef unsigned int u32;

__device__ __forceinline__ void gload16(const void* g, void* l){
  __builtin_amdgcn_global_load_lds(
      (const __attribute__((address_space(1))) u32*)g,
      (__attribute__((address_space(3))) u32*)l, 16, 0, 0);
}

__device__ __forceinline__ unsigned short bf16rn(float x){
  unsigned u = __float_as_uint(x);
  return (unsigned short)((u + 0x7fffu + ((u >> 16) & 1u)) >> 16);
}

// ---- numpy pairwise sum-of-squares over 256 elems (PW_BLOCKSIZE=128) ----
template<int STRIDE>
__device__ __forceinline__ float np_sumsq256(const float* __restrict__ a){
  float res0 = 0.f, res1 = 0.f;
  #pragma unroll
  for (int h = 0; h < 2; h++){
    const float* p = a + (size_t)h * 128 * STRIDE;
    float r[8];
    #pragma unroll
    for (int j = 0; j < 8; j++){ float x = p[(size_t)j * STRIDE]; r[j] = __fmul_rn(x, x); }
    for (int i = 8; i < 128; i += 8){
      #pragma unroll
      for (int j = 0; j < 8; j++){
        float x = p[(size_t)(i + j) * STRIDE];
        r[j] = __fadd_rn(r[j], __fmul_rn(x, x));
      }
    }
    float s = __fadd_rn(__fadd_rn(__fadd_rn(r[0], r[1]), __fadd_rn(r[2], r[3])),
                        __fadd_rn(__fadd_rn(r[4], r[5]), __fadd_rn(r[6], r[7])));
    if (h == 0) res0 = s; else res1 = s;
  }
  return __fadd_rn(res0, res1);
}

// ---------------- prep: bf16(rn) codebook + np-exact ee ----------------
__global__ void k_prep2(const float* __restrict__ cb, float* __restrict__ out){
  const int k = blockIdx.x * 256 + threadIdx.x;   // 8 blocks
  unsigned short* eh = (unsigned short*)(out + EH_OFF);
  const float* row = cb + (size_t)k * CC;
  for (int c = 0; c < CC; c++) eh[k * CC + c] = bf16rn(row[c]);
  out[EE_OFF + k] = np_sumsq256<1>(row);
}

// ---------------- zz[n] = np-pairwise sum_c feats^2 ----------------
__global__ void k_zz(const float* __restrict__ feats, float* __restrict__ out){
  const int n = blockIdx.x * 256 + threadIdx.x;   // 256 blocks
  const int b = n >> 12, hw = n & 4095;
  out[ZZ_OFF + n] = np_sumsq256<HW>(feats + (size_t)b * CC * HW + hw);
}

// ---------------- main MFMA kernel: 256 rows x 2048 codes, 4 waves, 2 blk/CU ----------------
// lds_e[buf][cs 16][sub 2][code 64][16B]; mfma(e, z) -> D[code][zrow]; 2 rowsets/wave
__global__ __launch_bounds__(256, 2)
void k_mfma(const float* __restrict__ feats, const float* __restrict__ cb,
            float* __restrict__ out){
  __shared__ __align__(16) unsigned char lds_e[2][32768];
  __shared__ float ee_lds[KK];
  __shared__ unsigned long long rowkey[256];
  __shared__ int cand[CAND_CAP];
  __shared__ int cand_n;
  __shared__ float lsum;

  const int t = threadIdx.x;             // 256
  const int w = t >> 6, l = t & 63;
  const int grp = l >> 5;
  const int lane31 = l & 31;
  const int n0 = blockIdx.x * 256;       // 256 blocks
  const int bi = n0 >> 12;
  const int hw0 = n0 & 4095;

  for (int i = t; i < KK; i += 256) ee_lds[i] = out[EE_OFF + i];
  if (t < 256) rowkey[t] = ~0ull;
  if (t == 0){ cand_n = 0; lsum = 0.f; }

  // ---- z fragments (B operand) for 2 rowsets of 32 rows each
  bf16x8 ah0[16], ah1[16];
  {
    const float* zb = feats + (size_t)bi * CC * HW + hw0 + w * 64 + lane31;
    #pragma unroll
    for (int cs = 0; cs < 16; ++cs){
      #pragma unroll
      for (int j = 0; j < 8; ++j){
        size_t co = (size_t)(cs * 16 + grp * 8 + j) * HW;
        ah0[cs][j] = (short)bf16rn(zb[co]);
        ah1[cs][j] = (short)bf16rn(zb[co + 32]);
      }
    }
  }

  const unsigned short* ehg = (const unsigned short*)(out + EH_OFF);

  // per-thread source element offsets for the 8 staging chunks
  int ofs_[8];
  #pragma unroll
  for (int i = 0; i < 8; ++i){
    int ix = i * 256 + t;
    int cd = ix & 63, g = (ix >> 6) & 1, cs = ix >> 7;
    ofs_[i] = cd * CC + cs * 16 + g * 8;
  }

#define STAGE(KT, B) { \
    const unsigned short* tb_ = ehg + (size_t)(KT) * (KTC * CC); \
    _Pragma("unroll") \
    for (int i_ = 0; i_ < 8; ++i_) \
      gload16(tb_ + ofs_[i_], &lds_e[B][(i_ * 256 + t) * 16]); }

#define COMPUTE(B) { \
    _Pragma("unroll") \
    for (int ii = 0; ii < 16; ++ii){ a00[ii]=0.f; a01[ii]=0.f; a10[ii]=0.f; a11[ii]=0.f; } \
    _Pragma("unroll") \
    for (int cs = 0; cs < 16; ++cs){ \
      const unsigned char* bp_ = &lds_e[B][(size_t)(cs * 2 + grp) * 1024 + lane31 * 16]; \
      bf16x8 e0_ = *(const bf16x8*)(bp_); \
      bf16x8 e1_ = *(const bf16x8*)(bp_ + 512); \
      a00 = __builtin_amdgcn_mfma_f32_32x32x16_bf16(e0_, ah0[cs], a00, 0, 0, 0); \
      a01 = __builtin_amdgcn_mfma_f32_32x32x16_bf16(e1_, ah0[cs], a01, 0, 0, 0); \
      a10 = __builtin_amdgcn_mfma_f32_32x32x16_bf16(e0_, ah1[cs], a10, 0, 0, 0); \
      a11 = __builtin_amdgcn_mfma_f32_32x32x16_bf16(e1_, ah1[cs], a11, 0, 0, 0); \
    } }

  f32x16 a00, a01, a10, a11;
  float m0 = 3e38f, m1 = 3e38f, ss0 = 0.f, ss1 = 0.f, inv0 = 0.f, inv1 = 0.f;

  STAGE(0, 0);
  __syncthreads();

  // fused loop: kt<32 = stats pass, kt>=32 = probs+cand pass
  for (int kt = 0; kt < 2 * KT_N; ++kt){
    const int tt = kt & 31;
    const int buf = kt & 1;
    if (kt < 2 * KT_N - 1) STAGE((kt + 1) & 31, buf ^ 1);
    COMPUTE(buf);
    const int eebase = tt * 64 + 4 * grp;
    if (kt < KT_N){
      #pragma unroll
      for (int r = 0; r < 16; ++r){
        int off = (r & 3) + 8 * (r >> 2);
        float e_lo = ee_lds[eebase + off], e_hi = ee_lds[eebase + off + 32];
        float s00 = e_lo - 2.f * a00[r];
        float s01 = e_hi - 2.f * a01[r];
        float s10 = e_lo - 2.f * a10[r];
        float s11 = e_hi - 2.f * a11[r];
        m0 = fminf(m0, fminf(s00, s01));
        m1 = fminf(m1, fminf(s10, s11));
        ss0 += __expf(-s00) + __expf(-s01);
        ss1 += __expf(-s10) + __expf(-s11);
      }
      if (kt == KT_N - 1){
        m0 = fminf(m0, __shfl_xor(m0, 32));
        m1 = fminf(m1, __shfl_xor(m1, 32));
        ss0 += __shfl_xor(ss0, 32);
        ss1 += __shfl_xor(ss1, 32);
        inv0 = 1.f / ss0; inv1 = 1.f / ss1;
      }
    } else {
      float* pb = out + (size_t)PROBS_OFF
                + (size_t)(bi * KK + tt * 64 + 4 * grp) * HW + hw0 + w * 64 + lane31;
      #pragma unroll
      for (int r = 0; r < 16; ++r){
        int off = (r & 3) + 8 * (r >> 2);
        float e_lo = ee_lds[eebase + off], e_hi = ee_lds[eebase + off + 32];
        float s00 = e_lo - 2.f * a00[r];
        float s01 = e_hi - 2.f * a01[r];
        float s10 = e_lo - 2.f * a10[r];
        float s11 = e_hi - 2.f * a11[r];
        float* p = pb + (size_t)off * HW;
        p[0]                    = __expf(-s00) * inv0;
        p[(size_t)32 * HW]      = __expf(-s01) * inv0;
        p[32]                   = __expf(-s10) * inv1;
        p[(size_t)32 * HW + 32] = __expf(-s11) * inv1;
        int cg = eebase + off;
        if (s00 <= m0 + TAU){
          int sl = atomicAdd(&cand_n, 1);
          if (sl < CAND_CAP) cand[sl] = ((w * 64 + lane31) << 16) | cg;
        }
        if (s01 <= m0 + TAU){
          int sl = atomicAdd(&cand_n, 1);
          if (sl < CAND_CAP) cand[sl] = ((w * 64 + lane31) << 16) | (cg + 32);
        }
        if (s10 <= m1 + TAU){
          int sl = atomicAdd(&cand_n, 1);
          if (sl < CAND_CAP) cand[sl] = ((w * 64 + 32 + lane31) << 16) | cg;
        }
        if (s11 <= m1 + TAU){
          int sl = atomicAdd(&cand_n, 1);
          if (sl < CAND_CAP) cand[sl] = ((w * 64 + 32 + lane31) << 16) | (cg + 32);
        }
      }
    }
    __syncthreads();
  }

  // ---- bit-exact rescore of candidates (numpy fp32 chain), first-min wins
  int nc = cand_n; if (nc > CAND_CAP) nc = CAND_CAP;
  for (int i = t; i < nc; i += 256){
    int rc = cand[i];
    int rl = rc >> 16, code = rc & 0xffff;
    int n = n0 + rl;
    const float* zp = feats + (size_t)(n >> 12) * CC * HW + (n & 4095);
    const float* ep = cb + (size_t)code * CC;
    float a = 0.f;
    #pragma unroll 8
    for (int c = 0; c < CC; ++c) a = __builtin_fmaf(zp[(size_t)c * HW], ep[c], a);
    float t1 = __fadd_rn(out[ZZ_OFF + n], ee_lds[code]);
    float d = __fadd_rn(t1, -2.f * a);
    unsigned long long key = ((unsigned long long)__float_as_uint(d) << 32) | (unsigned)code;
    atomicMin(&rowkey[rl], key);
  }
  __syncthreads();

  out[IDX_OFF + n0 + t] = (float)(int)(rowkey[t] & 0xffffffffu);

  // ---- loss: each thread handles its row
  {
    int code = (int)(rowkey[t] & 0xffffffffu);
    const float* ep = cb + (size_t)code * CC;
    const float* zp = feats + (size_t)bi * CC * HW + hw0 + t;
    float s = 0.f;
    for (int c = 0; c < CC; ++c){
      float dz = ep[c] - zp[(size_t)c * HW];
      s = __builtin_fmaf(dz, dz, s);
    }
    atomicAdd(&lsum, s);
  }
  __syncthreads();
  if (t == 0) atomicAdd(out + LOSS_OFF, lsum * (1.25f / 16777216.f));
}

// ---------------- z_q gather (bit-exact copy; overwrites scratch) ----------------
__global__ void k_zq(const float* __restrict__ cb, float* __restrict__ out){
  const int f4 = blockIdx.x * 256 + threadIdx.x;  // 16384 blocks
  const int f = f4 * 4;
  const int b = f >> 20;
  const int rem = f & 1048575;
  const int c = rem >> 12;
  const int hw = rem & 4095;
  const int n = b * HW + hw;
  const float* idxf = out + IDX_OFF;
  float4 iv = *(const float4*)(idxf + n);
  float4 o;
  o.x = cb[(size_t)((int)iv.x) * CC + c];
  o.y = cb[(size_t)((int)iv.y) * CC + c];
  o.z = cb[(size_t)((int)iv.z) * CC + c];
  o.w = cb[(size_t)((int)iv.w) * CC + c];
  *(float4*)(out + f) = o;
}

extern "C" void kernel_launch(void* const* d_in, const int* in_sizes, int n_in,
                              void* d_out, int out_size, void* d_ws, size_t ws_size,
                              hipStream_t stream){
  const float* feats = (const float*)d_in[0];
  const float* cb    = (const float*)d_in[1];
  float* out = (float*)d_out;

  (void)hipMemsetAsync(out + LOSS_OFF, 0, sizeof(float), stream);
  hipLaunchKernelGGL(k_prep2, dim3(8),     dim3(256), 0, stream, cb, out);
  hipLaunchKernelGGL(k_zz,    dim3(256),   dim3(256), 0, stream, feats, out);
  hipLaunchKernelGGL(k_mfma,  dim3(256),   dim3(256), 0, stream, feats, cb, out);
  hipLaunchKernelGGL(k_zq,    dim3(16384), dim3(256), 0, stream, cb, out);
}

// Round 10
// 488.811 us; speedup vs baseline: 1.1909x; 1.0881x over previous
//
#include <hip/hip_runtime.h>

#define HW 4096
#define CC 256
#define KK 2048
#define BB 16
#define NN (BB*HW)          // 65536
#define RPB 128             // rows per block

// d_out layout (floats): [z_q 16777216][idx 65536][loss 1][probs 134217728]
#define ZQ_SZ   (BB*CC*HW)
#define IDX_OFF ZQ_SZ
#define LOSS_OFF (IDX_OFF + NN)
#define PROBS_OFF (LOSS_OFF + 1)

// scratch parked in z_q region (float offsets), overwritten by k_zq at the end
#define EH_OFF 0          // eh[K][C] bf16 (rn) = 262144 floats
#define EE_OFF 262144     // ee_np[K] f32
#define ZZ_OFF 264192     // zz_np[N] f32

#define TAU 0.01f
#define CAND_CAP 512
#define KTC 64            // codes per k-tile
#define KT_N 32           // tiles per pass

typedef short bf16x8 __attribute__((ext_vector_type(8)));
typedef float f32x16 __attribute__((ext_vector_type(16)));
typedef unsigned int u32;

__device__ __forceinline__ void gload16(const void* g, void* l){
  __builtin_amdgcn_global_load_lds(
      (const __attribute__((address_space(1))) u32*)g,
      (__attribute__((address_space(3))) u32*)l, 16, 0, 0);
}

__device__ __forceinline__ unsigned short bf16rn(float x){
  unsigned u = __float_as_uint(x);
  return (unsigned short)((u + 0x7fffu + ((u >> 16) & 1u)) >> 16);
}

// ---- numpy pairwise sum-of-squares over 256 elems (PW_BLOCKSIZE=128) ----
template<int STRIDE>
__device__ __forceinline__ float np_sumsq256(const float* __restrict__ a){
  float res0 = 0.f, res1 = 0.f;
  #pragma unroll
  for (int h = 0; h < 2; h++){
    const float* p = a + (size_t)h * 128 * STRIDE;
    float r[8];
    #pragma unroll
    for (int j = 0; j < 8; j++){ float x = p[(size_t)j * STRIDE]; r[j] = __fmul_rn(x, x); }
    for (int i = 8; i < 128; i += 8){
      #pragma unroll
      for (int j = 0; j < 8; j++){
        float x = p[(size_t)(i + j) * STRIDE];
        r[j] = __fadd_rn(r[j], __fmul_rn(x, x));
      }
    }
    float s = __fadd_rn(__fadd_rn(__fadd_rn(r[0], r[1]), __fadd_rn(r[2], r[3])),
                        __fadd_rn(__fadd_rn(r[4], r[5]), __fadd_rn(r[6], r[7])));
    if (h == 0) res0 = s; else res1 = s;
  }
  return __fadd_rn(res0, res1);
}

// ---------------- prep: bf16(rn) codebook + np-exact ee ----------------
__global__ void k_prep2(const float* __restrict__ cb, float* __restrict__ out){
  const int k = blockIdx.x * 256 + threadIdx.x;   // 8 blocks
  unsigned short* eh = (unsigned short*)(out + EH_OFF);
  const float* row = cb + (size_t)k * CC;
  for (int c = 0; c < CC; c++) eh[k * CC + c] = bf16rn(row[c]);
  out[EE_OFF + k] = np_sumsq256<1>(row);
}

// ---------------- zz[n] = np-pairwise sum_c feats^2 ----------------
__global__ void k_zz(const float* __restrict__ feats, float* __restrict__ out){
  const int n = blockIdx.x * 256 + threadIdx.x;   // 256 blocks
  const int b = n >> 12, hw = n & 4095;
  out[ZZ_OFF + n] = np_sumsq256<HW>(feats + (size_t)b * CC * HW + hw);
}

// ---------------- main MFMA kernel: 128 rows x 2048 codes, 4 waves, 512 blocks ----------------
// lds_e[buf][cs 16][sub 2][code 64][16B]; mfma(e, z) -> D[code][zrow]
__global__ __launch_bounds__(256, 2)
void k_mfma(const float* __restrict__ feats, const float* __restrict__ cb,
            float* __restrict__ out){
  __shared__ __align__(16) unsigned char lds_e[2][32768];
  __shared__ float ee_lds[KK];
  __shared__ unsigned long long rowkey[RPB];
  __shared__ int cand[CAND_CAP];
  __shared__ int cand_n;
  __shared__ float lsum;

  const int t = threadIdx.x;             // 256
  const int w = t >> 6, l = t & 63;
  const int grp = l >> 5;
  const int lane31 = l & 31;
  const int n0 = blockIdx.x * RPB;       // 512 blocks
  const int bi = n0 >> 12;
  const int hw0 = n0 & 4095;
  const int myhw = hw0 + w * 32 + lane31;

  for (int i = t; i < KK; i += 256) ee_lds[i] = out[EE_OFF + i];
  if (t < RPB) rowkey[t] = ~0ull;
  if (t == 0){ cand_n = 0; lsum = 0.f; }

  // ---- z fragments (B operand): z[c][myhw], resident in VGPRs
  bf16x8 ah0[16];
  {
    const float* zb = feats + (size_t)bi * CC * HW + myhw;
    #pragma unroll
    for (int cs = 0; cs < 16; ++cs){
      #pragma unroll
      for (int j = 0; j < 8; ++j)
        ah0[cs][j] = (short)bf16rn(zb[(size_t)(cs * 16 + grp * 8 + j) * HW]);
    }
  }

  const unsigned short* ehg = (const unsigned short*)(out + EH_OFF);

  // per-thread source element offsets for the 8 staging chunks
  int ofs_[8];
  #pragma unroll
  for (int i = 0; i < 8; ++i){
    int ix = i * 256 + t;
    int cd = ix & 63, g = (ix >> 6) & 1, cs = ix >> 7;
    ofs_[i] = cd * CC + cs * 16 + g * 8;
  }

#define STAGE(KT, B) { \
    const unsigned short* tb_ = ehg + (size_t)(KT) * (KTC * CC); \
    _Pragma("unroll") \
    for (int i_ = 0; i_ < 8; ++i_) \
      gload16(tb_ + ofs_[i_], &lds_e[B][(i_ * 256 + t) * 16]); }

#define COMPUTE(B) { \
    _Pragma("unroll") \
    for (int ii = 0; ii < 16; ++ii){ accA[ii] = 0.f; accB[ii] = 0.f; } \
    _Pragma("unroll") \
    for (int cs = 0; cs < 16; ++cs){ \
      const unsigned char* bp_ = &lds_e[B][(size_t)(cs * 2 + grp) * 1024 + lane31 * 16]; \
      bf16x8 e0_ = *(const bf16x8*)(bp_); \
      bf16x8 e1_ = *(const bf16x8*)(bp_ + 512); \
      accA = __builtin_amdgcn_mfma_f32_32x32x16_bf16(e0_, ah0[cs], accA, 0, 0, 0); \
      accB = __builtin_amdgcn_mfma_f32_32x32x16_bf16(e1_, ah0[cs], accB, 0, 0, 0); \
    } }

  f32x16 accA, accB;
  float m0 = 3e38f, ss0 = 0.f, inv0 = 0.f;

  STAGE(0, 0);
  __syncthreads();

  // fused loop: kt<32 = stats pass, kt>=32 = probs+cand pass
  for (int kt = 0; kt < 2 * KT_N; ++kt){
    const int tt = kt & 31;
    const int buf = kt & 1;
    if (kt < 2 * KT_N - 1) STAGE((kt + 1) & 31, buf ^ 1);
    COMPUTE(buf);
    const int eebase = tt * 64 + 4 * grp;
    if (kt < KT_N){
      #pragma unroll
      for (int r = 0; r < 16; ++r){
        int off = (r & 3) + 8 * (r >> 2);
        float s0 = ee_lds[eebase + off]      - 2.f * accA[r];
        float s1 = ee_lds[eebase + off + 32] - 2.f * accB[r];
        m0 = fminf(m0, fminf(s0, s1));
        ss0 += __expf(-s0) + __expf(-s1);   // s in [-1,1]: shift-free
      }
      if (kt == KT_N - 1){
        m0 = fminf(m0, __shfl_xor(m0, 32));
        ss0 += __shfl_xor(ss0, 32);
        inv0 = 1.f / ss0;
      }
    } else {
      float* pb = out + (size_t)PROBS_OFF
                + (size_t)(bi * KK + eebase) * HW + myhw;
      #pragma unroll
      for (int r = 0; r < 16; ++r){
        int off = (r & 3) + 8 * (r >> 2);
        float s0 = ee_lds[eebase + off]      - 2.f * accA[r];
        float s1 = ee_lds[eebase + off + 32] - 2.f * accB[r];
        float* p = pb + (size_t)off * HW;
        p[0]               = __expf(-s0) * inv0;
        p[(size_t)32 * HW] = __expf(-s1) * inv0;
        int cg = eebase + off;
        if (s0 <= m0 + TAU){
          int sl = atomicAdd(&cand_n, 1);
          if (sl < CAND_CAP) cand[sl] = ((w * 32 + lane31) << 16) | cg;
        }
        if (s1 <= m0 + TAU){
          int sl = atomicAdd(&cand_n, 1);
          if (sl < CAND_CAP) cand[sl] = ((w * 32 + lane31) << 16) | (cg + 32);
        }
      }
    }
    __syncthreads();
  }

  // ---- bit-exact rescore of candidates (numpy fp32 chain), first-min wins
  int nc = cand_n; if (nc > CAND_CAP) nc = CAND_CAP;
  for (int i = t; i < nc; i += 256){
    int rc = cand[i];
    int rl = rc >> 16, code = rc & 0xffff;
    int n = n0 + rl;
    const float* zp = feats + (size_t)(n >> 12) * CC * HW + (n & 4095);
    const float* ep = cb + (size_t)code * CC;
    float a = 0.f;
    #pragma unroll 8
    for (int c = 0; c < CC; ++c) a = __builtin_fmaf(zp[(size_t)c * HW], ep[c], a);
    float t1 = __fadd_rn(out[ZZ_OFF + n], ee_lds[code]);
    float d = __fadd_rn(t1, -2.f * a);
    unsigned long long key = ((unsigned long long)__float_as_uint(d) << 32) | (unsigned)code;
    atomicMin(&rowkey[rl], key);
  }
  __syncthreads();

  if (t < RPB) out[IDX_OFF + n0 + t] = (float)(int)(rowkey[t] & 0xffffffffu);

  // ---- loss: threads 0..127 each handle one row
  if (t < RPB){
    int code = (int)(rowkey[t] & 0xffffffffu);
    const float* ep = cb + (size_t)code * CC;
    const float* zp = feats + (size_t)bi * CC * HW + hw0 + t;
    float s = 0.f;
    for (int c = 0; c < CC; ++c){
      float dz = ep[c] - zp[(size_t)c * HW];
      s = __builtin_fmaf(dz, dz, s);
    }
    atomicAdd(&lsum, s);
  }
  __syncthreads();
  if (t == 0) atomicAdd(out + LOSS_OFF, lsum * (1.25f / 16777216.f));
}

// ---------------- z_q gather (bit-exact copy; overwrites scratch) ----------------
__global__ void k_zq(const float* __restrict__ cb, float* __restrict__ out){
  const int f4 = blockIdx.x * 256 + threadIdx.x;  // 16384 blocks
  const int f = f4 * 4;
  const int b = f >> 20;
  const int rem = f & 1048575;
  const int c = rem >> 12;
  const int hw = rem & 4095;
  const int n = b * HW + hw;
  const float* idxf = out + IDX_OFF;
  float4 iv = *(const float4*)(idxf + n);
  float4 o;
  o.x = cb[(size_t)((int)iv.x) * CC + c];
  o.y = cb[(size_t)((int)iv.y) * CC + c];
  o.z = cb[(size_t)((int)iv.z) * CC + c];
  o.w = cb[(size_t)((int)iv.w) * CC + c];
  *(float4*)(out + f) = o;
}

extern "C" void kernel_launch(void* const* d_in, const int* in_sizes, int n_in,
                              void* d_out, int out_size, void* d_ws, size_t ws_size,
                              hipStream_t stream){
  const float* feats = (const float*)d_in[0];
  const float* cb    = (const float*)d_in[1];
  float* out = (float*)d_out;

  (void)hipMemsetAsync(out + LOSS_OFF, 0, sizeof(float), stream);
  hipLaunchKernelGGL(k_prep2, dim3(8),     dim3(256), 0, stream, cb, out);
  hipLaunchKernelGGL(k_zz,    dim3(256),   dim3(256), 0, stream, feats, out);
  hipLaunchKernelGGL(k_mfma,  dim3(512),   dim3(256), 0, stream, feats, cb, out);
  hipLaunchKernelGGL(k_zq,    dim3(16384), dim3(256), 0, stream, cb, out);
}